// Round 1
// baseline (414.110 us; speedup 1.0000x reference)
//
#include <hip/hip_runtime.h>
#include <hip/hip_bf16.h>

// ZoomTransformerBlock: B=2, N=2048, D=1024, H=16, DH=64, DF=4096
// Pipeline (all bf16 MFMA internally, fp32 accum; threshold is 2% of |ref|max):
//   1. transpose-cast weights fp32->bf16 (B^T layout for MFMA B-operand)
//   2. cast dist fp32->bf16
//   3. LN1(x) -> h_bf16
//   4. GEMM qkv: h @ Wqkv + b -> scatter q[B,H,N,DH], k[B,H,N,DH], vT[B,H,DH,N]
//   5. flash attention w/ -gamma*dist bias -> ao bf16 [B,N,D]
//   6. GEMM proj: d_out = x + ao @ Wp + b        (x1 kept in d_out)
//   7. LN2(d_out) -> h2_bf16
//   8. GEMM mlp1: gelu_exact(h2 @ W1 + b1) -> g bf16
//   9. GEMM mlp2: d_out += g @ W2 + b2
//
// Workspace layout (bytes), total 72 MiB:
//   0         wqkvT  [3072][1024] bf16   6291456
//   6291456   wprojT [1024][1024] bf16   2097152
//   8388608   w1T    [4096][1024] bf16   8388608
//   16777216  w2T    [1024][4096] bf16   8388608
//   25165824  distb  [2048][2048] bf16   8388608
//   33554432  h      [4096][1024] bf16   8388608   }
//   41943040  q      [2,16,2048,64] bf16 8388608   }  g [4096][4096] bf16
//   50331648  k      same                8388608   }  reuses h..vT (33554432)
//   58720256  vT     [2,16,64,2048]     8388608   }
//   67108864  ao     [4096][1024] bf16   8388608      h2 reuses ao slot

#define SCALE_ 0.03125f   // D^-0.5 = 1/32
#define EPS_   1e-5f

typedef unsigned short u16;
typedef __attribute__((ext_vector_type(8))) short short8;
typedef __attribute__((ext_vector_type(4))) float f32x4;
typedef __attribute__((ext_vector_type(4))) unsigned short u16x4;

__device__ inline float b2f(u16 u){ unsigned x = ((unsigned)u) << 16; float f; __builtin_memcpy(&f, &x, 4); return f; }
__device__ inline u16 f2b(float f){ __hip_bfloat16 h = __float2bfloat16(f); u16 u; __builtin_memcpy(&u, &h, 2); return u; }

// ---------------- transpose + cast: src [K][N] f32 -> dst [N][K] bf16 ----------------
__global__ __launch_bounds__(256) void transpose_cast(const float* __restrict__ src,
                                                      u16* __restrict__ dst, int K, int N) {
    __shared__ float t[32][33];
    int nb = blockIdx.x * 32, kb = blockIdx.y * 32;
    int tx = threadIdx.x & 31, ty = threadIdx.x >> 5;
    for (int i = 0; i < 4; i++) {
        int r = ty + i * 8;
        t[r][tx] = src[(size_t)(kb + r) * N + nb + tx];
    }
    __syncthreads();
    for (int i = 0; i < 4; i++) {
        int r = ty + i * 8;
        dst[(size_t)(nb + r) * K + kb + tx] = f2b(t[tx][r]);
    }
}

// ---------------- elementwise cast f32 -> bf16 (dist) ----------------
__global__ __launch_bounds__(256) void cast_bf16(const float* __restrict__ src,
                                                 u16* __restrict__ dst, int n4) {
    int i = blockIdx.x * 256 + threadIdx.x;
    if (i < n4) {
        float4 v = ((const float4*)src)[i];
        u16x4 o;
        o[0] = f2b(v.x); o[1] = f2b(v.y); o[2] = f2b(v.z); o[3] = f2b(v.w);
        ((u16x4*)dst)[i] = o;
    }
}

// ---------------- LayerNorm row (D=1024) f32 -> bf16 ----------------
__global__ __launch_bounds__(256) void ln_bf16(const float* __restrict__ x,
                                               const float* __restrict__ w,
                                               const float* __restrict__ b,
                                               u16* __restrict__ out) {
    int row = blockIdx.x, t = threadIdx.x;
    float4 v = ((const float4*)(x + (size_t)row * 1024))[t];
    float s1 = v.x + v.y + v.z + v.w;
    float s2 = v.x * v.x + v.y * v.y + v.z * v.z + v.w * v.w;
    for (int o = 32; o > 0; o >>= 1) { s1 += __shfl_xor(s1, o); s2 += __shfl_xor(s2, o); }
    __shared__ float a1[4], a2[4];
    if ((t & 63) == 0) { a1[t >> 6] = s1; a2[t >> 6] = s2; }
    __syncthreads();
    s1 = a1[0] + a1[1] + a1[2] + a1[3];
    s2 = a2[0] + a2[1] + a2[2] + a2[3];
    float mu = s1 * (1.0f / 1024.0f);
    float var = s2 * (1.0f / 1024.0f) - mu * mu;
    float rs = rsqrtf(var + EPS_);
    float4 wv = ((const float4*)w)[t];
    float4 bv = ((const float4*)b)[t];
    u16x4 o;
    o[0] = f2b((v.x - mu) * rs * wv.x + bv.x);
    o[1] = f2b((v.y - mu) * rs * wv.y + bv.y);
    o[2] = f2b((v.z - mu) * rs * wv.z + bv.z);
    o[3] = f2b((v.w - mu) * rs * wv.w + bv.w);
    ((u16x4*)(out + (size_t)row * 1024))[t] = o;
}

// ---------------- bf16 GEMM: C[M,N] = A[M,K] @ Bt[N,K]^T, templated epilogue ----------------
// MODE 0: qkv scatter (+bias)   MODE 1: outf = res + acc + bias
// MODE 2: outb = gelu(acc+bias) MODE 3: outf += acc + bias
template <int MODE>
__global__ __launch_bounds__(256) void gemm_bf16(
    const u16* __restrict__ A, const u16* __restrict__ Bt,
    const float* __restrict__ bias, int M, int N, int K,
    const float* __restrict__ res, float* __restrict__ outf, u16* __restrict__ outb,
    u16* __restrict__ qp, u16* __restrict__ kp, u16* __restrict__ vtp) {
    __shared__ u16 As[128 * 40];   // [row][k] pad 40 (bank-conflict break)
    __shared__ u16 Bs[128 * 40];   // [col][k]
    int br = blockIdx.y * 128, bc = blockIdx.x * 128;
    int tid = threadIdx.x;
    int w = tid >> 6, lane = tid & 63, g = lane >> 4, ln = lane & 15;
    int wr = (w >> 1) * 64, wc = (w & 1) * 64;
    f32x4 acc[4][4] = {};
    int srow = tid >> 1, sseg = (tid & 1) * 16;
    const u16* Aptr = A + (size_t)(br + srow) * K + sseg;
    const u16* Bptr = Bt + (size_t)(bc + srow) * K + sseg;
    for (int kt = 0; kt < K; kt += 32) {
        __syncthreads();
        *(short8*)&As[srow * 40 + sseg]     = *(const short8*)(Aptr + kt);
        *(short8*)&As[srow * 40 + sseg + 8] = *(const short8*)(Aptr + kt + 8);
        *(short8*)&Bs[srow * 40 + sseg]     = *(const short8*)(Bptr + kt);
        *(short8*)&Bs[srow * 40 + sseg + 8] = *(const short8*)(Bptr + kt + 8);
        __syncthreads();
        short8 af[4], bfr[4];
        for (int m = 0; m < 4; m++) af[m]  = *(const short8*)&As[(wr + m * 16 + ln) * 40 + g * 8];
        for (int n = 0; n < 4; n++) bfr[n] = *(const short8*)&Bs[(wc + n * 16 + ln) * 40 + g * 8];
        for (int m = 0; m < 4; m++)
            for (int n = 0; n < 4; n++)
                acc[m][n] = __builtin_amdgcn_mfma_f32_16x16x32_bf16(af[m], bfr[n], acc[m][n], 0, 0, 0);
    }
    for (int m = 0; m < 4; m++) {
        int row0 = br + wr + m * 16 + g * 4;
        for (int n = 0; n < 4; n++) {
            int col = bc + wc + n * 16 + ln;
            float bv = bias[col];
            for (int r = 0; r < 4; r++) {
                float v = acc[m][n][r] + bv;
                int mr = row0 + r;
                if constexpr (MODE == 0) {
                    int which = col >> 10, cc = col & 1023, hh = cc >> 6, dh = cc & 63;
                    int bb = mr >> 11, nn = mr & 2047;
                    size_t bh = (size_t)(bb * 16 + hh);
                    if (which == 0)      qp[((bh * 2048 + nn) << 6) + dh] = f2b(v);
                    else if (which == 1) kp[((bh * 2048 + nn) << 6) + dh] = f2b(v);
                    else                 vtp[((bh * 64 + dh) << 11) + nn] = f2b(v);
                } else if constexpr (MODE == 1) {
                    size_t idx = (size_t)mr * 1024 + col;
                    outf[idx] = res[idx] + v;
                } else if constexpr (MODE == 2) {
                    float gl = 0.5f * v * (1.0f + erff(v * 0.7071067811865476f));
                    outb[(size_t)mr * 4096 + col] = f2b(gl);
                } else {
                    size_t idx = (size_t)mr * 1024 + col;
                    outf[idx] = outf[idx] + v;
                }
            }
        }
    }
}

// ---------------- flash attention: grid (32 q-tiles, 32 bh), 4 waves/wg ----------------
__global__ __launch_bounds__(256) void attn_fwd(
    const u16* __restrict__ qg, const u16* __restrict__ kg, const u16* __restrict__ vtg,
    const u16* __restrict__ distb, const float* __restrict__ gamma, u16* __restrict__ ao) {
    __shared__ u16 Ks[64 * 72];     // [kv][d] pad 72
    __shared__ u16 Vs[64 * 72];     // [d][kv] pad 72
    __shared__ u16 Ps[4][16 * 72];  // per-wave [q16][kv64] pad 72
    int qt = blockIdx.x, bh = blockIdx.y;
    int b = bh >> 4, h = bh & 15;
    int tid = threadIdx.x, w = tid >> 6, lane = tid & 63, g = lane >> 4, ln = lane & 15;
    float gam = gamma[bh];
    // Q fragments (A-operand: row = lane&15, k = (lane>>4)*8+j)
    const u16* qrow = qg + ((size_t)bh * 2048 + qt * 64 + w * 16 + ln) * 64;
    short8 qf0 = *(const short8*)(qrow + g * 8);
    short8 qf1 = *(const short8*)(qrow + 32 + g * 8);
    float mrow[4] = {-1e30f, -1e30f, -1e30f, -1e30f};
    float lrow[4] = {0, 0, 0, 0};
    f32x4 acco[4] = {};
    int srow = tid >> 2, scol = (tid & 3) * 16;
    for (int kt = 0; kt < 32; kt++) {
        __syncthreads();
        {   // stage K tile [64 kv][64 d] and V^T tile [64 d][64 kv]
            const u16* kpp = kg + ((size_t)bh * 2048 + kt * 64 + srow) * 64 + scol;
            *(short8*)&Ks[srow * 72 + scol]     = *(const short8*)(kpp);
            *(short8*)&Ks[srow * 72 + scol + 8] = *(const short8*)(kpp + 8);
            const u16* vpp = vtg + ((size_t)bh * 64 + srow) * 2048 + kt * 64 + scol;
            *(short8*)&Vs[srow * 72 + scol]     = *(const short8*)(vpp);
            *(short8*)&Vs[srow * 72 + scol + 8] = *(const short8*)(vpp + 8);
        }
        __syncthreads();
        // S = Q K^T  (4 kv-blocks of 16, K-dim 64 = 2 mfma steps)
        f32x4 sa[4] = {};
        for (int nb = 0; nb < 4; nb++) {
            short8 kf0 = *(const short8*)&Ks[(nb * 16 + ln) * 72 + g * 8];
            short8 kf1 = *(const short8*)&Ks[(nb * 16 + ln) * 72 + 32 + g * 8];
            sa[nb] = __builtin_amdgcn_mfma_f32_16x16x32_bf16(qf0, kf0, sa[nb], 0, 0, 0);
            sa[nb] = __builtin_amdgcn_mfma_f32_16x16x32_bf16(qf1, kf1, sa[nb], 0, 0, 0);
        }
        // bias + online softmax (C layout: col = ln (kv), row16 = g*4+r (q))
        int qbase = qt * 64 + w * 16 + g * 4;
        for (int r = 0; r < 4; r++) {
            const u16* drow = distb + (size_t)(qbase + r) * 2048 + kt * 64 + ln;
            float sv[4], pm = -1e30f;
            for (int nb = 0; nb < 4; nb++) {
                float d = b2f(drow[nb * 16]);
                float s = sa[nb][r] * SCALE_ - gam * d;
                sv[nb] = s;
                pm = fmaxf(pm, s);
            }
            for (int o = 1; o < 16; o <<= 1) pm = fmaxf(pm, __shfl_xor(pm, o));
            float nm = fmaxf(mrow[r], pm);
            float alpha = __expf(mrow[r] - nm);
            mrow[r] = nm;
            float ps = 0.0f;
            for (int nb = 0; nb < 4; nb++) {
                float p = __expf(sv[nb] - nm);
                ps += p;
                Ps[w][(g * 4 + r) * 72 + nb * 16 + ln] = f2b(p);
            }
            for (int o = 1; o < 16; o <<= 1) ps += __shfl_xor(ps, o);
            lrow[r] = lrow[r] * alpha + ps;
            for (int db = 0; db < 4; db++) acco[db][r] *= alpha;
        }
        // PV: out[q][d] += P[q][kv] V[kv][d]   (P via per-wave LDS; V^T for contiguous kv)
        short8 pf0 = *(const short8*)&Ps[w][ln * 72 + g * 8];
        short8 pf1 = *(const short8*)&Ps[w][ln * 72 + 32 + g * 8];
        for (int db = 0; db < 4; db++) {
            short8 vf0 = *(const short8*)&Vs[(db * 16 + ln) * 72 + g * 8];
            short8 vf1 = *(const short8*)&Vs[(db * 16 + ln) * 72 + 32 + g * 8];
            acco[db] = __builtin_amdgcn_mfma_f32_16x16x32_bf16(pf0, vf0, acco[db], 0, 0, 0);
            acco[db] = __builtin_amdgcn_mfma_f32_16x16x32_bf16(pf1, vf1, acco[db], 0, 0, 0);
        }
    }
    // out: ao[b][n][h*64+d] bf16
    for (int r = 0; r < 4; r++) {
        int n = qt * 64 + w * 16 + g * 4 + r;
        float inv = 1.0f / lrow[r];
        for (int db = 0; db < 4; db++)
            ao[(size_t)(b * 2048 + n) * 1024 + h * 64 + db * 16 + ln] = f2b(acco[db][r] * inv);
    }
}

extern "C" void kernel_launch(void* const* d_in, const int* in_sizes, int n_in,
                              void* d_out, int out_size, void* d_ws, size_t ws_size,
                              hipStream_t stream) {
    const float* x     = (const float*)d_in[0];
    const float* gamma = (const float*)d_in[1];
    const float* dist  = (const float*)d_in[2];
    const float* ln1w  = (const float*)d_in[3];
    const float* ln1b  = (const float*)d_in[4];
    const float* qkvw  = (const float*)d_in[5];
    const float* qkvb  = (const float*)d_in[6];
    const float* projw = (const float*)d_in[7];
    const float* projb = (const float*)d_in[8];
    const float* ln2w  = (const float*)d_in[9];
    const float* ln2b  = (const float*)d_in[10];
    const float* w1    = (const float*)d_in[11];
    const float* b1    = (const float*)d_in[12];
    const float* w2    = (const float*)d_in[13];
    const float* b2    = (const float*)d_in[14];
    float* out = (float*)d_out;
    char* ws = (char*)d_ws;
    u16* wqkvT  = (u16*)(ws + 0);
    u16* wprojT = (u16*)(ws + 6291456);
    u16* w1T    = (u16*)(ws + 8388608);
    u16* w2T    = (u16*)(ws + 16777216);
    u16* distb  = (u16*)(ws + 25165824);
    u16* hb     = (u16*)(ws + 33554432);
    u16* qb     = (u16*)(ws + 41943040);
    u16* kb     = (u16*)(ws + 50331648);
    u16* vtb    = (u16*)(ws + 58720256);
    u16* aob    = (u16*)(ws + 67108864);
    u16* gb     = hb;    // mlp1 output reuses h..vT region (33.5 MB, dead by then)
    u16* h2b    = aob;   // ln2 output reuses ao slot (dead after proj)

    dim3 blk(256);
    transpose_cast<<<dim3(3072 / 32, 1024 / 32), blk, 0, stream>>>(qkvw, wqkvT, 1024, 3072);
    transpose_cast<<<dim3(1024 / 32, 1024 / 32), blk, 0, stream>>>(projw, wprojT, 1024, 1024);
    transpose_cast<<<dim3(4096 / 32, 1024 / 32), blk, 0, stream>>>(w1, w1T, 1024, 4096);
    transpose_cast<<<dim3(1024 / 32, 4096 / 32), blk, 0, stream>>>(w2, w2T, 4096, 1024);
    cast_bf16<<<4096, blk, 0, stream>>>(dist, distb, 2048 * 2048 / 4);
    ln_bf16<<<4096, blk, 0, stream>>>(x, ln1w, ln1b, hb);
    gemm_bf16<0><<<dim3(24, 32), blk, 0, stream>>>(hb, wqkvT, qkvb, 4096, 3072, 1024,
                                                   nullptr, nullptr, nullptr, qb, kb, vtb);
    attn_fwd<<<dim3(32, 32), blk, 0, stream>>>(qb, kb, vtb, distb, gamma, aob);
    gemm_bf16<1><<<dim3(8, 32), blk, 0, stream>>>(aob, wprojT, projb, 4096, 1024, 1024,
                                                  x, out, nullptr, nullptr, nullptr, nullptr);
    ln_bf16<<<4096, blk, 0, stream>>>(out, ln2w, ln2b, h2b);
    gemm_bf16<2><<<dim3(32, 32), blk, 0, stream>>>(h2b, w1T, b1, 4096, 4096, 1024,
                                                   nullptr, nullptr, gb, nullptr, nullptr, nullptr);
    gemm_bf16<3><<<dim3(8, 32), blk, 0, stream>>>(gb, w2T, b2, 4096, 1024, 4096,
                                                  nullptr, out, nullptr, nullptr, nullptr, nullptr);
}

// Round 2
// 389.782 us; speedup vs baseline: 1.0624x; 1.0624x over previous
//
#include <hip/hip_runtime.h>
#include <hip/hip_bf16.h>

// ZoomTransformerBlock: B=2, N=2048, D=1024, H=16, DH=64, DF=4096
// R2: GEMM -> m97 structure (global_load_lds width=16, linear LDS);
//     attention -> swapped-QK^T lane-local softmax (q = lane&15), exp2 folding,
//     vectorized dist/P/out accesses, s_setprio around MFMA clusters.
//
// Workspace layout (bytes), total 72 MiB (see R1 comments).

#define SCALE_ 0.03125f   // D^-0.5 = 1/32
#define EPS_   1e-5f
#define LOG2E_ 1.4426950408889634f

typedef unsigned short u16;
typedef __attribute__((ext_vector_type(8))) short short8;
typedef __attribute__((ext_vector_type(4))) float f32x4;
typedef __attribute__((ext_vector_type(4))) unsigned short u16x4;

__device__ inline float b2f(u16 u){ unsigned x = ((unsigned)u) << 16; float f; __builtin_memcpy(&f, &x, 4); return f; }
__device__ inline u16 f2b(float f){ __hip_bfloat16 h = __float2bfloat16(f); u16 u; __builtin_memcpy(&u, &h, 2); return u; }

// async global->LDS, 16B per lane; lds dest must be wave-uniform base (lane*16 auto)
__device__ inline void glds16(const u16* g, u16* l) {
    __builtin_amdgcn_global_load_lds(
        (const __attribute__((address_space(1))) void*)g,
        (__attribute__((address_space(3))) void*)l, 16, 0, 0);
}

// ---------------- transpose + cast: src [K][N] f32 -> dst [N][K] bf16 ----------------
__global__ __launch_bounds__(256) void transpose_cast(const float* __restrict__ src,
                                                      u16* __restrict__ dst, int K, int N) {
    __shared__ float t[32][33];
    int nb = blockIdx.x * 32, kb = blockIdx.y * 32;
    int tx = threadIdx.x & 31, ty = threadIdx.x >> 5;
    for (int i = 0; i < 4; i++) {
        int r = ty + i * 8;
        t[r][tx] = src[(size_t)(kb + r) * N + nb + tx];
    }
    __syncthreads();
    for (int i = 0; i < 4; i++) {
        int r = ty + i * 8;
        dst[(size_t)(nb + r) * K + kb + tx] = f2b(t[tx][r]);
    }
}

// ---------------- elementwise cast f32 -> bf16 (dist) ----------------
__global__ __launch_bounds__(256) void cast_bf16(const float* __restrict__ src,
                                                 u16* __restrict__ dst, int n4) {
    int i = blockIdx.x * 256 + threadIdx.x;
    if (i < n4) {
        float4 v = ((const float4*)src)[i];
        u16x4 o;
        o[0] = f2b(v.x); o[1] = f2b(v.y); o[2] = f2b(v.z); o[3] = f2b(v.w);
        ((u16x4*)dst)[i] = o;
    }
}

// ---------------- LayerNorm row (D=1024) f32 -> bf16 ----------------
__global__ __launch_bounds__(256) void ln_bf16(const float* __restrict__ x,
                                               const float* __restrict__ w,
                                               const float* __restrict__ b,
                                               u16* __restrict__ out) {
    int row = blockIdx.x, t = threadIdx.x;
    float4 v = ((const float4*)(x + (size_t)row * 1024))[t];
    float s1 = v.x + v.y + v.z + v.w;
    float s2 = v.x * v.x + v.y * v.y + v.z * v.z + v.w * v.w;
    for (int o = 32; o > 0; o >>= 1) { s1 += __shfl_xor(s1, o); s2 += __shfl_xor(s2, o); }
    __shared__ float a1[4], a2[4];
    if ((t & 63) == 0) { a1[t >> 6] = s1; a2[t >> 6] = s2; }
    __syncthreads();
    s1 = a1[0] + a1[1] + a1[2] + a1[3];
    s2 = a2[0] + a2[1] + a2[2] + a2[3];
    float mu = s1 * (1.0f / 1024.0f);
    float var = s2 * (1.0f / 1024.0f) - mu * mu;
    float rs = rsqrtf(var + EPS_);
    float4 wv = ((const float4*)w)[t];
    float4 bv = ((const float4*)b)[t];
    u16x4 o;
    o[0] = f2b((v.x - mu) * rs * wv.x + bv.x);
    o[1] = f2b((v.y - mu) * rs * wv.y + bv.y);
    o[2] = f2b((v.z - mu) * rs * wv.z + bv.z);
    o[3] = f2b((v.w - mu) * rs * wv.w + bv.w);
    ((u16x4*)(out + (size_t)row * 1024))[t] = o;
}

// ---------------- bf16 GEMM (m97 structure): C[M,N] = A[M,K] @ Bt[N,K]^T ----------------
// MODE 0: qkv scatter (+bias)   MODE 1: outf = res + acc + bias
// MODE 2: outb = gelu(acc+bias) MODE 3: outf += acc + bias
template <int MODE>
__global__ __launch_bounds__(256) void gemm_bf16(
    const u16* __restrict__ A, const u16* __restrict__ Bt,
    const float* __restrict__ bias, int M, int N, int K,
    const float* __restrict__ res, float* __restrict__ outf, u16* __restrict__ outb,
    u16* __restrict__ qp, u16* __restrict__ kp, u16* __restrict__ vtp) {
    __shared__ u16 As[128 * 32];   // [row][k] linear (global_load_lds needs contiguous)
    __shared__ u16 Bs[128 * 32];   // [col][k]
    int br = blockIdx.y * 128, bc = blockIdx.x * 128;
    int tid = threadIdx.x;
    int w = tid >> 6, lane = tid & 63, g = lane >> 4, ln = lane & 15;
    int wr = (w >> 1) * 64, wc = (w & 1) * 64;
    f32x4 acc[4][4] = {};
    // staging: wave w stages rows [w*32, w*32+32) of A and B; 1KB per instr (16 rows)
    int srow = w * 32 + (lane >> 2);
    int scol = (lane & 3) * 8;
    const u16* Ap = A + (size_t)(br + srow) * K + scol;
    const u16* Bp = Bt + (size_t)(bc + srow) * K + scol;
    size_t row16 = (size_t)16 * K;
    u16* lA0 = &As[(w * 32) * 32];
    u16* lA1 = &As[(w * 32 + 16) * 32];
    u16* lB0 = &Bs[(w * 32) * 32];
    u16* lB1 = &Bs[(w * 32 + 16) * 32];
    for (int kt = 0; kt < K; kt += 32) {
        __syncthreads();
        glds16(Ap + kt, lA0);
        glds16(Ap + kt + row16, lA1);
        glds16(Bp + kt, lB0);
        glds16(Bp + kt + row16, lB1);
        __syncthreads();   // compiler emits vmcnt(0) drain here
        short8 af[4], bfr[4];
        for (int m = 0; m < 4; m++) af[m]  = *(const short8*)&As[(wr + m * 16 + ln) * 32 + g * 8];
        for (int n = 0; n < 4; n++) bfr[n] = *(const short8*)&Bs[(wc + n * 16 + ln) * 32 + g * 8];
        for (int m = 0; m < 4; m++)
            for (int n = 0; n < 4; n++)
                acc[m][n] = __builtin_amdgcn_mfma_f32_16x16x32_bf16(af[m], bfr[n], acc[m][n], 0, 0, 0);
    }
    for (int m = 0; m < 4; m++) {
        int row0 = br + wr + m * 16 + g * 4;
        for (int n = 0; n < 4; n++) {
            int col = bc + wc + n * 16 + ln;
            float bv = bias[col];
            for (int r = 0; r < 4; r++) {
                float v = acc[m][n][r] + bv;
                int mr = row0 + r;
                if constexpr (MODE == 0) {
                    int which = col >> 10, cc = col & 1023, hh = cc >> 6, dh = cc & 63;
                    int bb = mr >> 11, nn = mr & 2047;
                    size_t bh = (size_t)(bb * 16 + hh);
                    if (which == 0)      qp[((bh * 2048 + nn) << 6) + dh] = f2b(v);
                    else if (which == 1) kp[((bh * 2048 + nn) << 6) + dh] = f2b(v);
                    else                 vtp[((bh * 64 + dh) << 11) + nn] = f2b(v);
                } else if constexpr (MODE == 1) {
                    size_t idx = (size_t)mr * 1024 + col;
                    outf[idx] = res[idx] + v;
                } else if constexpr (MODE == 2) {
                    float gl = 0.5f * v * (1.0f + erff(v * 0.7071067811865476f));
                    outb[(size_t)mr * 4096 + col] = f2b(gl);
                } else {
                    size_t idx = (size_t)mr * 1024 + col;
                    outf[idx] = outf[idx] + v;
                }
            }
        }
    }
}

// ---------------- flash attention, swapped QK^T: lane owns q = lane&15 ----------------
// grid (32 q-tiles, 32 bh), 4 waves/wg, each wave: 16 q rows, kv tile 64.
__global__ __launch_bounds__(256) void attn_fwd(
    const u16* __restrict__ qg, const u16* __restrict__ kg, const u16* __restrict__ vtg,
    const u16* __restrict__ distb, const float* __restrict__ gamma, u16* __restrict__ ao) {
    __shared__ u16 Ks[64 * 72];     // [kv][d] pad 72
    __shared__ u16 Vs[64 * 72];     // [d][kv] pad 72 (V^T)
    __shared__ u16 Ps[4][16 * 72];  // per-wave [q16][kv64] pad 72
    int qt = blockIdx.x, bh = blockIdx.y;
    int b = bh >> 4, h = bh & 15;
    int tid = threadIdx.x, w = tid >> 6, lane = tid & 63, g = lane >> 4, ln = lane & 15;
    float gam2 = gamma[bh] * LOG2E_;
    const float SC2 = SCALE_ * LOG2E_;
    int qglob = qt * 64 + w * 16 + ln;
    const u16* qrow = qg + ((size_t)bh * 2048 + qglob) * 64;
    short8 qf0 = *(const short8*)(qrow + g * 8);
    short8 qf1 = *(const short8*)(qrow + 32 + g * 8);
    const u16* dbase = distb + (size_t)qglob * 2048 + g * 4;  // + kt*64 + nb*16
    float m2 = -3.0e38f;   // running max (log2 domain)
    float lsum = 0.0f;
    f32x4 acco[4] = {};    // out^T: acco[db][r] = out[d=db*16+g*4+r][q=ln]
    int srow = tid >> 2, scol = (tid & 3) * 16;
    for (int kt = 0; kt < 32; kt++) {
        __syncthreads();
        {   // stage K tile [64 kv][64 d] and V^T tile [64 d][64 kv]
            const u16* kpp = kg + ((size_t)bh * 2048 + kt * 64 + srow) * 64 + scol;
            *(short8*)&Ks[srow * 72 + scol]     = *(const short8*)(kpp);
            *(short8*)&Ks[srow * 72 + scol + 8] = *(const short8*)(kpp + 8);
            const u16* vpp = vtg + ((size_t)bh * 64 + srow) * 2048 + kt * 64 + scol;
            *(short8*)&Vs[srow * 72 + scol]     = *(const short8*)(vpp);
            *(short8*)&Vs[srow * 72 + scol + 8] = *(const short8*)(vpp + 8);
        }
        __syncthreads();
        // S^T = K Q^T : D[kv_local=g*4+r][q=ln], 4 kv-blocks of 16
        f32x4 sa[4] = {};
        __builtin_amdgcn_s_setprio(1);
        for (int nb = 0; nb < 4; nb++) {
            short8 kf0 = *(const short8*)&Ks[(nb * 16 + ln) * 72 + g * 8];
            short8 kf1 = *(const short8*)&Ks[(nb * 16 + ln) * 72 + 32 + g * 8];
            sa[nb] = __builtin_amdgcn_mfma_f32_16x16x32_bf16(kf0, qf0, sa[nb], 0, 0, 0);
            sa[nb] = __builtin_amdgcn_mfma_f32_16x16x32_bf16(kf1, qf1, sa[nb], 0, 0, 0);
        }
        __builtin_amdgcn_s_setprio(0);
        // bias + online softmax, all in log2 domain; lane holds 16 kv for q=ln
        float sv[4][4];
        float pm = -3.0e38f;
        for (int nb = 0; nb < 4; nb++) {
            u16x4 dv = *(const u16x4*)(dbase + kt * 64 + nb * 16);
            for (int r = 0; r < 4; r++) {
                float s = sa[nb][r] * SC2 - gam2 * b2f(dv[r]);
                sv[nb][r] = s;
                pm = fmaxf(pm, s);
            }
        }
        pm = fmaxf(pm, __shfl_xor(pm, 16));
        pm = fmaxf(pm, __shfl_xor(pm, 32));
        float nm = fmaxf(m2, pm);
        float alpha = __builtin_exp2f(m2 - nm);
        m2 = nm;
        float ps = 0.0f;
        for (int nb = 0; nb < 4; nb++) {
            u16x4 pw;
            for (int r = 0; r < 4; r++) {
                float p = __builtin_exp2f(sv[nb][r] - nm);
                ps += p;
                pw[r] = f2b(p);
            }
            *(u16x4*)&Ps[w][ln * 72 + nb * 16 + g * 4] = pw;  // P[q=ln][kv] row-major
        }
        ps += __shfl_xor(ps, 16);
        ps += __shfl_xor(ps, 32);
        lsum = lsum * alpha + ps;
        for (int db = 0; db < 4; db++) acco[db] *= alpha;
        // PV^T: out^T[d][q] += V^T[d][kv] P^T[kv][q]; A=V^T frag, B=P^T frag
        short8 pf0 = *(const short8*)&Ps[w][ln * 72 + g * 8];
        short8 pf1 = *(const short8*)&Ps[w][ln * 72 + 32 + g * 8];
        __builtin_amdgcn_s_setprio(1);
        for (int db = 0; db < 4; db++) {
            short8 vf0 = *(const short8*)&Vs[(db * 16 + ln) * 72 + g * 8];
            short8 vf1 = *(const short8*)&Vs[(db * 16 + ln) * 72 + 32 + g * 8];
            acco[db] = __builtin_amdgcn_mfma_f32_16x16x32_bf16(vf0, pf0, acco[db], 0, 0, 0);
            acco[db] = __builtin_amdgcn_mfma_f32_16x16x32_bf16(vf1, pf1, acco[db], 0, 0, 0);
        }
        __builtin_amdgcn_s_setprio(0);
    }
    // out: ao[b][n=qglob][h*64 + d], d = db*16 + g*4 + r  -> u16x4 per db
    float inv = 1.0f / lsum;
    u16* aop = ao + (size_t)(b * 2048 + qglob) * 1024 + h * 64 + g * 4;
    for (int db = 0; db < 4; db++) {
        u16x4 o;
        for (int r = 0; r < 4; r++) o[r] = f2b(acco[db][r] * inv);
        *(u16x4*)(aop + db * 16) = o;
    }
}

extern "C" void kernel_launch(void* const* d_in, const int* in_sizes, int n_in,
                              void* d_out, int out_size, void* d_ws, size_t ws_size,
                              hipStream_t stream) {
    const float* x     = (const float*)d_in[0];
    const float* gamma = (const float*)d_in[1];
    const float* dist  = (const float*)d_in[2];
    const float* ln1w  = (const float*)d_in[3];
    const float* ln1b  = (const float*)d_in[4];
    const float* qkvw  = (const float*)d_in[5];
    const float* qkvb  = (const float*)d_in[6];
    const float* projw = (const float*)d_in[7];
    const float* projb = (const float*)d_in[8];
    const float* ln2w  = (const float*)d_in[9];
    const float* ln2b  = (const float*)d_in[10];
    const float* w1    = (const float*)d_in[11];
    const float* b1    = (const float*)d_in[12];
    const float* w2    = (const float*)d_in[13];
    const float* b2    = (const float*)d_in[14];
    float* out = (float*)d_out;
    char* ws = (char*)d_ws;
    u16* wqkvT  = (u16*)(ws + 0);
    u16* wprojT = (u16*)(ws + 6291456);
    u16* w1T    = (u16*)(ws + 8388608);
    u16* w2T    = (u16*)(ws + 16777216);
    u16* distb  = (u16*)(ws + 25165824);
    u16* hb     = (u16*)(ws + 33554432);
    u16* qb     = (u16*)(ws + 41943040);
    u16* kb     = (u16*)(ws + 50331648);
    u16* vtb    = (u16*)(ws + 58720256);
    u16* aob    = (u16*)(ws + 67108864);
    u16* gb     = hb;    // mlp1 output reuses h..vT region (dead by then)
    u16* h2b    = aob;   // ln2 output reuses ao slot (dead after proj)

    dim3 blk(256);
    transpose_cast<<<dim3(3072 / 32, 1024 / 32), blk, 0, stream>>>(qkvw, wqkvT, 1024, 3072);
    transpose_cast<<<dim3(1024 / 32, 1024 / 32), blk, 0, stream>>>(projw, wprojT, 1024, 1024);
    transpose_cast<<<dim3(4096 / 32, 1024 / 32), blk, 0, stream>>>(w1, w1T, 1024, 4096);
    transpose_cast<<<dim3(1024 / 32, 4096 / 32), blk, 0, stream>>>(w2, w2T, 4096, 1024);
    cast_bf16<<<4096, blk, 0, stream>>>(dist, distb, 2048 * 2048 / 4);
    ln_bf16<<<4096, blk, 0, stream>>>(x, ln1w, ln1b, hb);
    gemm_bf16<0><<<dim3(24, 32), blk, 0, stream>>>(hb, wqkvT, qkvb, 4096, 3072, 1024,
                                                   nullptr, nullptr, nullptr, qb, kb, vtb);
    attn_fwd<<<dim3(32, 32), blk, 0, stream>>>(qb, kb, vtb, distb, gamma, aob);
    gemm_bf16<1><<<dim3(8, 32), blk, 0, stream>>>(aob, wprojT, projb, 4096, 1024, 1024,
                                                  x, out, nullptr, nullptr, nullptr, nullptr);
    ln_bf16<<<4096, blk, 0, stream>>>(out, ln2w, ln2b, h2b);
    gemm_bf16<2><<<dim3(32, 32), blk, 0, stream>>>(h2b, w1T, b1, 4096, 4096, 1024,
                                                   nullptr, nullptr, gb, nullptr, nullptr, nullptr);
    gemm_bf16<3><<<dim3(8, 32), blk, 0, stream>>>(gb, w2T, b2, 4096, 1024, 4096,
                                                  nullptr, out, nullptr, nullptr, nullptr, nullptr);
}

// Round 3
// 297.752 us; speedup vs baseline: 1.3908x; 1.3091x over previous
//
#include <hip/hip_runtime.h>
#include <hip/hip_bf16.h>

// ZoomTransformerBlock: B=2, N=2048, D=1024, H=16, DH=64, DF=4096
// R3: GEMM -> BK=64, XOR-swizzled LDS via pre-swizzled global source (rule #21),
//            BN=64 tile variant for proj/mlp2 (2 wg/CU instead of 1);
//     attn -> linear 64x64 K/V tiles with XOR slot swizzle (reg-staged),
//            double-buffered LDS, ONE barrier/tile, async-STAGE split (T14),
//            defer-max (T13), scale/log2e folded into q and dist.

#define SCALE_ 0.03125f   // D^-0.5 = 1/32
#define EPS_   1e-5f
#define LOG2E_ 1.4426950408889634f
#define SC2_   (SCALE_ * LOG2E_)

typedef unsigned short u16;
typedef __attribute__((ext_vector_type(8))) short short8;
typedef __attribute__((ext_vector_type(4))) float f32x4;
typedef __attribute__((ext_vector_type(4))) unsigned short u16x4;

__device__ inline float b2f(u16 u){ unsigned x = ((unsigned)u) << 16; float f; __builtin_memcpy(&f, &x, 4); return f; }
__device__ inline u16 f2b(float f){ __hip_bfloat16 h = __float2bfloat16(f); u16 u; __builtin_memcpy(&u, &h, 2); return u; }

// async global->LDS, 16B per lane; LDS dest = wave-uniform base + lane*16 (linear)
__device__ inline void glds16(const u16* g, u16* l) {
    __builtin_amdgcn_global_load_lds(
        (const __attribute__((address_space(1))) void*)g,
        (__attribute__((address_space(3))) void*)l, 16, 0, 0);
}

// ---------------- transpose + cast: src [K][N] f32 -> dst [N][K] bf16 ----------------
__global__ __launch_bounds__(256) void transpose_cast(const float* __restrict__ src,
                                                      u16* __restrict__ dst, int K, int N) {
    __shared__ float t[32][33];
    int nb = blockIdx.x * 32, kb = blockIdx.y * 32;
    int tx = threadIdx.x & 31, ty = threadIdx.x >> 5;
    for (int i = 0; i < 4; i++) {
        int r = ty + i * 8;
        t[r][tx] = src[(size_t)(kb + r) * N + nb + tx];
    }
    __syncthreads();
    for (int i = 0; i < 4; i++) {
        int r = ty + i * 8;
        dst[(size_t)(nb + r) * K + kb + tx] = f2b(t[tx][r]);
    }
}

// ---------------- elementwise cast+scale f32 -> bf16 (dist * log2e) ----------------
__global__ __launch_bounds__(256) void cast_scale_bf16(const float* __restrict__ src,
                                                       u16* __restrict__ dst, int n4, float scale) {
    int i = blockIdx.x * 256 + threadIdx.x;
    if (i < n4) {
        float4 v = ((const float4*)src)[i];
        u16x4 o;
        o[0] = f2b(v.x * scale); o[1] = f2b(v.y * scale);
        o[2] = f2b(v.z * scale); o[3] = f2b(v.w * scale);
        ((u16x4*)dst)[i] = o;
    }
}

// ---------------- LayerNorm row (D=1024) f32 -> bf16 ----------------
__global__ __launch_bounds__(256) void ln_bf16(const float* __restrict__ x,
                                               const float* __restrict__ w,
                                               const float* __restrict__ b,
                                               u16* __restrict__ out) {
    int row = blockIdx.x, t = threadIdx.x;
    float4 v = ((const float4*)(x + (size_t)row * 1024))[t];
    float s1 = v.x + v.y + v.z + v.w;
    float s2 = v.x * v.x + v.y * v.y + v.z * v.z + v.w * v.w;
    for (int o = 32; o > 0; o >>= 1) { s1 += __shfl_xor(s1, o); s2 += __shfl_xor(s2, o); }
    __shared__ float a1[4], a2[4];
    if ((t & 63) == 0) { a1[t >> 6] = s1; a2[t >> 6] = s2; }
    __syncthreads();
    s1 = a1[0] + a1[1] + a1[2] + a1[3];
    s2 = a2[0] + a2[1] + a2[2] + a2[3];
    float mu = s1 * (1.0f / 1024.0f);
    float var = s2 * (1.0f / 1024.0f) - mu * mu;
    float rs = rsqrtf(var + EPS_);
    float4 wv = ((const float4*)w)[t];
    float4 bv = ((const float4*)b)[t];
    u16x4 o;
    o[0] = f2b((v.x - mu) * rs * wv.x + bv.x);
    o[1] = f2b((v.y - mu) * rs * wv.y + bv.y);
    o[2] = f2b((v.z - mu) * rs * wv.z + bv.z);
    o[3] = f2b((v.w - mu) * rs * wv.w + bv.w);
    ((u16x4*)(out + (size_t)row * 1024))[t] = o;
}

// ---------------- bf16 GEMM: C[M,N] = A[M,K] @ Bt[N,K]^T, BK=64, XOR-swizzled ----------------
// MODE 0: qkv scatter (+bias, q pre-scaled by SCALE*LOG2E)
// MODE 1: outf = res + acc + bias    MODE 2: outb = gelu(acc+bias)   MODE 3: outf += acc + bias
template <int MODE, int BN>
__global__ __launch_bounds__(256) void gemm_bf16(
    const u16* __restrict__ A, const u16* __restrict__ Bt,
    const float* __restrict__ bias, int M, int N, int K,
    const float* __restrict__ res, float* __restrict__ outf, u16* __restrict__ outb,
    u16* __restrict__ qp, u16* __restrict__ kp, u16* __restrict__ vtp) {
    constexpr int NN = BN / 32;          // n-frags per wave
    __shared__ u16 As[128 * 64];
    __shared__ u16 Bs[BN * 64];
    int br = blockIdx.y * 128, bc = blockIdx.x * BN;
    int tid = threadIdx.x;
    int w = tid >> 6, lane = tid & 63, g = lane >> 4, ln = lane & 15;
    int wr = (w >> 1) * 64, wc = (w & 1) * (BN / 2);
    f32x4 acc[4][NN] = {};
    // staging: 1KB/instr = 8 rows x 128B; LDS linear; GLOBAL col pre-swizzled:
    // LDS[row][slot = lane&7] must hold global slot (lane&7)^(row&7), row&7 = lane>>3
    int sgcol = (((lane & 7) ^ (lane >> 3)) << 3);
    int arow = w * 32 + (lane >> 3);
    int brow = w * (BN / 4) + (lane >> 3);
    const u16* Ap = A + (size_t)(br + arow) * K + sgcol;
    const u16* Bp = Bt + (size_t)(bc + brow) * K + sgcol;
    u16* lA = &As[(w * 32) * 64];
    u16* lB = &Bs[(w * (BN / 4)) * 64];
    size_t rstep = (size_t)8 * K;
    for (int kt = 0; kt < K; kt += 64) {
        __syncthreads();
        #pragma unroll
        for (int i = 0; i < 4; i++) glds16(Ap + kt + i * rstep, lA + i * 512);
        #pragma unroll
        for (int i = 0; i < BN / 32; i++) glds16(Bp + kt + i * rstep, lB + i * 512);
        __syncthreads();
        #pragma unroll
        for (int kk = 0; kk < 2; kk++) {
            int so = (((kk << 2) + g) ^ (ln & 7)) << 3;   // swizzled k-slot
            short8 af[4], bfr[NN];
            #pragma unroll
            for (int m = 0; m < 4; m++)  af[m]  = *(const short8*)&As[(wr + m * 16 + ln) * 64 + so];
            #pragma unroll
            for (int n = 0; n < NN; n++) bfr[n] = *(const short8*)&Bs[(wc + n * 16 + ln) * 64 + so];
            #pragma unroll
            for (int m = 0; m < 4; m++)
                #pragma unroll
                for (int n = 0; n < NN; n++)
                    acc[m][n] = __builtin_amdgcn_mfma_f32_16x16x32_bf16(af[m], bfr[n], acc[m][n], 0, 0, 0);
        }
    }
    #pragma unroll
    for (int m = 0; m < 4; m++) {
        int row0 = br + wr + m * 16 + g * 4;
        #pragma unroll
        for (int n = 0; n < NN; n++) {
            int col = bc + wc + n * 16 + ln;
            float bv = bias[col];
            if constexpr (MODE == 0) {
                int which = col >> 10, cc = col & 1023, hh = cc >> 6, dh = cc & 63;
                int bb = row0 >> 11, nn0 = row0 & 2047;
                size_t bh = (size_t)(bb * 16 + hh);
                if (which == 0) {
                    for (int r = 0; r < 4; r++)
                        qp[((bh * 2048 + nn0 + r) << 6) + dh] = f2b((acc[m][n][r] + bv) * SC2_);
                } else if (which == 1) {
                    for (int r = 0; r < 4; r++)
                        kp[((bh * 2048 + nn0 + r) << 6) + dh] = f2b(acc[m][n][r] + bv);
                } else {
                    u16x4 o;
                    for (int r = 0; r < 4; r++) o[r] = f2b(acc[m][n][r] + bv);
                    *(u16x4*)&vtp[((bh * 64 + dh) << 11) + nn0] = o;
                }
            } else if constexpr (MODE == 1) {
                for (int r = 0; r < 4; r++) {
                    size_t idx = (size_t)(row0 + r) * 1024 + col;
                    outf[idx] = res[idx] + acc[m][n][r] + bv;
                }
            } else if constexpr (MODE == 2) {
                for (int r = 0; r < 4; r++) {
                    float v = acc[m][n][r] + bv;
                    float gl = 0.5f * v * (1.0f + erff(v * 0.7071067811865476f));
                    outb[(size_t)(row0 + r) * 4096 + col] = f2b(gl);
                }
            } else {
                for (int r = 0; r < 4; r++) {
                    size_t idx = (size_t)(row0 + r) * 1024 + col;
                    outf[idx] = outf[idx] + acc[m][n][r] + bv;
                }
            }
        }
    }
}

// ---------------- flash attention: swapped QK^T, dbuf LDS, 1 barrier/tile ----------------
// grid (32 q-tiles, 32 bh), 4 waves/wg; q pre-scaled by SCALE*LOG2E, dist by LOG2E.
__global__ __launch_bounds__(256) void attn_fwd(
    const u16* __restrict__ qg, const u16* __restrict__ kg, const u16* __restrict__ vtg,
    const u16* __restrict__ distb, const float* __restrict__ gamma, u16* __restrict__ ao) {
    __shared__ u16 Ks[2][64 * 64];   // [kv][d] linear, XOR slot swizzle
    __shared__ u16 Vs[2][64 * 64];   // [d][kv] (V^T), same swizzle
    __shared__ u16 Ps[4][16 * 64];   // per-wave [q16][kv64], same swizzle
    int qt = blockIdx.x, bh = blockIdx.y;
    int b = bh >> 4, h = bh & 15;
    int tid = threadIdx.x, w = tid >> 6, lane = tid & 63, g = lane >> 4, ln = lane & 15;
    float gam = gamma[bh];
    int qglob = qt * 64 + w * 16 + ln;
    const u16* qrow = qg + ((size_t)bh * 2048 + qglob) * 64;
    short8 qf0 = *(const short8*)(qrow + g * 8);
    short8 qf1 = *(const short8*)(qrow + 32 + g * 8);
    const u16* dbase = distb + (size_t)qglob * 2048 + g * 4;
    float m2 = -3.0e38f, lsum = 0.0f;
    f32x4 acco[4] = {};    // out^T: acco[db][r] = out[d=db*16+g*4+r][q=ln]
    // staging: thread -> row tid>>2, slots 2c,2c+1 (c=tid&3); swizzled LDS write
    int srow = tid >> 2, sc = (tid & 3) * 2;
    int ss0 = ((sc ^ (srow & 7)) << 3), ss1 = (((sc + 1) ^ (srow & 7)) << 3);
    const u16* kgp = kg + ((size_t)bh * 2048 + srow) * 64 + sc * 8;
    const u16* vgp = vtg + ((size_t)bh * 64 + srow) * 2048 + sc * 8;
    {   // prologue: tile 0
        short8 a0 = *(const short8*)(kgp);
        short8 a1 = *(const short8*)(kgp + 8);
        short8 c0 = *(const short8*)(vgp);
        short8 c1 = *(const short8*)(vgp + 8);
        *(short8*)&Ks[0][srow * 64 + ss0] = a0;
        *(short8*)&Ks[0][srow * 64 + ss1] = a1;
        *(short8*)&Vs[0][srow * 64 + ss0] = c0;
        *(short8*)&Vs[0][srow * 64 + ss1] = c1;
    }
    u16x4 dcv[4];
    #pragma unroll
    for (int nb = 0; nb < 4; nb++) dcv[nb] = *(const u16x4*)(dbase + nb * 16);
    __syncthreads();
    int cur = 0;
    int so0 = (g ^ (ln & 7)) << 3, so1 = ((4 + g) ^ (ln & 7)) << 3;
    for (int kt = 0; kt < 32; kt++) {
        // async-STAGE split: issue next tile's global loads NOW, consume after PV
        short8 kr0, kr1, vr0, vr1;
        u16x4 dnx[4];
        if (kt < 31) {
            kr0 = *(const short8*)(kgp + (kt + 1) * 4096);
            kr1 = *(const short8*)(kgp + (kt + 1) * 4096 + 8);
            vr0 = *(const short8*)(vgp + (kt + 1) * 64);
            vr1 = *(const short8*)(vgp + (kt + 1) * 64 + 8);
            #pragma unroll
            for (int nb = 0; nb < 4; nb++)
                dnx[nb] = *(const u16x4*)(dbase + (kt + 1) * 64 + nb * 16);
        }
        // S^T = K Q^T : sa[nb][r] = S[kv=nb*16+g*4+r][q=ln]
        f32x4 sa[4] = {};
        __builtin_amdgcn_s_setprio(1);
        #pragma unroll
        for (int nb = 0; nb < 4; nb++) {
            short8 kf0 = *(const short8*)&Ks[cur][(nb * 16 + ln) * 64 + so0];
            short8 kf1 = *(const short8*)&Ks[cur][(nb * 16 + ln) * 64 + so1];
            sa[nb] = __builtin_amdgcn_mfma_f32_16x16x32_bf16(kf0, qf0, sa[nb], 0, 0, 0);
            sa[nb] = __builtin_amdgcn_mfma_f32_16x16x32_bf16(kf1, qf1, sa[nb], 0, 0, 0);
        }
        __builtin_amdgcn_s_setprio(0);
        // softmax in log2 domain (scales pre-folded): s = sa - gam*distl2
        float sv[4][4], pm = -3.0e38f;
        #pragma unroll
        for (int nb = 0; nb < 4; nb++)
            #pragma unroll
            for (int r = 0; r < 4; r++) {
                float s = sa[nb][r] - gam * b2f(dcv[nb][r]);
                sv[nb][r] = s;
                pm = fmaxf(pm, s);
            }
        pm = fmaxf(pm, __shfl_xor(pm, 16));
        pm = fmaxf(pm, __shfl_xor(pm, 32));
        if (!__all(pm - m2 <= 8.0f)) {   // defer-max: rescale only on real growth
            float nm = fmaxf(m2, pm);
            float al = __builtin_exp2f(m2 - nm);
            m2 = nm;
            lsum *= al;
            #pragma unroll
            for (int db = 0; db < 4; db++) acco[db] *= al;
        }
        float ps = 0.0f;
        #pragma unroll
        for (int nb = 0; nb < 4; nb++) {
            u16x4 pw;
            #pragma unroll
            for (int r = 0; r < 4; r++) {
                float p = __builtin_exp2f(sv[nb][r] - m2);
                ps += p;
                pw[r] = f2b(p);
            }
            int off = nb * 16 + g * 4;
            *(u16x4*)&Ps[w][ln * 64 + (((off >> 3) ^ (ln & 7)) << 3) + (off & 7)] = pw;
        }
        ps += __shfl_xor(ps, 16);
        ps += __shfl_xor(ps, 32);
        lsum += ps;
        // PV^T: out^T[d][q] += V^T[d][kv] P^T[kv][q]
        short8 pf0 = *(const short8*)&Ps[w][ln * 64 + so0];
        short8 pf1 = *(const short8*)&Ps[w][ln * 64 + so1];
        __builtin_amdgcn_s_setprio(1);
        #pragma unroll
        for (int db = 0; db < 4; db++) {
            short8 vf0 = *(const short8*)&Vs[cur][(db * 16 + ln) * 64 + so0];
            short8 vf1 = *(const short8*)&Vs[cur][(db * 16 + ln) * 64 + so1];
            acco[db] = __builtin_amdgcn_mfma_f32_16x16x32_bf16(vf0, pf0, acco[db], 0, 0, 0);
            acco[db] = __builtin_amdgcn_mfma_f32_16x16x32_bf16(vf1, pf1, acco[db], 0, 0, 0);
        }
        __builtin_amdgcn_s_setprio(0);
        if (kt < 31) {   // write-late: regs -> other buffer, ONE barrier/tile
            int nx = cur ^ 1;
            *(short8*)&Ks[nx][srow * 64 + ss0] = kr0;
            *(short8*)&Ks[nx][srow * 64 + ss1] = kr1;
            *(short8*)&Vs[nx][srow * 64 + ss0] = vr0;
            *(short8*)&Vs[nx][srow * 64 + ss1] = vr1;
            #pragma unroll
            for (int nb = 0; nb < 4; nb++) dcv[nb] = dnx[nb];
            __syncthreads();
            cur = nx;
        }
    }
    float inv = 1.0f / lsum;
    u16* aop = ao + (size_t)(b * 2048 + qglob) * 1024 + h * 64 + g * 4;
    #pragma unroll
    for (int db = 0; db < 4; db++) {
        u16x4 o;
        #pragma unroll
        for (int r = 0; r < 4; r++) o[r] = f2b(acco[db][r] * inv);
        *(u16x4*)(aop + db * 16) = o;
    }
}

extern "C" void kernel_launch(void* const* d_in, const int* in_sizes, int n_in,
                              void* d_out, int out_size, void* d_ws, size_t ws_size,
                              hipStream_t stream) {
    const float* x     = (const float*)d_in[0];
    const float* gamma = (const float*)d_in[1];
    const float* dist  = (const float*)d_in[2];
    const float* ln1w  = (const float*)d_in[3];
    const float* ln1b  = (const float*)d_in[4];
    const float* qkvw  = (const float*)d_in[5];
    const float* qkvb  = (const float*)d_in[6];
    const float* projw = (const float*)d_in[7];
    const float* projb = (const float*)d_in[8];
    const float* ln2w  = (const float*)d_in[9];
    const float* ln2b  = (const float*)d_in[10];
    const float* w1    = (const float*)d_in[11];
    const float* b1    = (const float*)d_in[12];
    const float* w2    = (const float*)d_in[13];
    const float* b2    = (const float*)d_in[14];
    float* out = (float*)d_out;
    char* ws = (char*)d_ws;
    u16* wqkvT  = (u16*)(ws + 0);
    u16* wprojT = (u16*)(ws + 6291456);
    u16* w1T    = (u16*)(ws + 8388608);
    u16* w2T    = (u16*)(ws + 16777216);
    u16* distb  = (u16*)(ws + 25165824);
    u16* hb     = (u16*)(ws + 33554432);
    u16* qb     = (u16*)(ws + 41943040);
    u16* kb     = (u16*)(ws + 50331648);
    u16* vtb    = (u16*)(ws + 58720256);
    u16* aob    = (u16*)(ws + 67108864);
    u16* gb     = hb;    // mlp1 output reuses h..vT region (dead by then)
    u16* h2b    = aob;   // ln2 output reuses ao slot (dead after proj)

    dim3 blk(256);
    transpose_cast<<<dim3(3072 / 32, 1024 / 32), blk, 0, stream>>>(qkvw, wqkvT, 1024, 3072);
    transpose_cast<<<dim3(1024 / 32, 1024 / 32), blk, 0, stream>>>(projw, wprojT, 1024, 1024);
    transpose_cast<<<dim3(4096 / 32, 1024 / 32), blk, 0, stream>>>(w1, w1T, 1024, 4096);
    transpose_cast<<<dim3(1024 / 32, 4096 / 32), blk, 0, stream>>>(w2, w2T, 4096, 1024);
    cast_scale_bf16<<<4096, blk, 0, stream>>>(dist, distb, 2048 * 2048 / 4, LOG2E_);
    ln_bf16<<<4096, blk, 0, stream>>>(x, ln1w, ln1b, hb);
    gemm_bf16<0, 128><<<dim3(24, 32), blk, 0, stream>>>(hb, wqkvT, qkvb, 4096, 3072, 1024,
                                                        nullptr, nullptr, nullptr, qb, kb, vtb);
    attn_fwd<<<dim3(32, 32), blk, 0, stream>>>(qb, kb, vtb, distb, gamma, aob);
    gemm_bf16<1, 64><<<dim3(16, 32), blk, 0, stream>>>(aob, wprojT, projb, 4096, 1024, 1024,
                                                       x, out, nullptr, nullptr, nullptr, nullptr);
    ln_bf16<<<4096, blk, 0, stream>>>(out, ln2w, ln2b, h2b);
    gemm_bf16<2, 128><<<dim3(32, 32), blk, 0, stream>>>(h2b, w1T, b1, 4096, 4096, 1024,
                                                        nullptr, nullptr, gb, nullptr, nullptr, nullptr);
    gemm_bf16<3, 64><<<dim3(16, 32), blk, 0, stream>>>(gb, w2T, b2, 4096, 1024, 4096,
                                                       nullptr, out, nullptr, nullptr, nullptr, nullptr);
}

// Round 4
// 297.165 us; speedup vs baseline: 1.3935x; 1.0020x over previous
//
#include <hip/hip_runtime.h>
#include <hip/hip_bf16.h>

// ZoomTransformerBlock: B=2, N=2048, D=1024, H=16, DH=64, DF=4096
// R4: qkv & mlp1 -> 8-phase 256^2 MFMA GEMM (8 waves, BK=32, 4-deep K-tile
//     pipeline, counted vmcnt(8), swizzled LDS, setprio);
//     attn -> f32 dist direct (cast kernel removed), lsum via ones-MFMA;
//     proj/mlp2 keep R3 structure.

#define SCALE_ 0.03125f   // D^-0.5 = 1/32
#define EPS_   1e-5f
#define LOG2E_ 1.4426950408889634f
#define SC2_   (SCALE_ * LOG2E_)

typedef unsigned short u16;
typedef __attribute__((ext_vector_type(8))) short short8;
typedef __attribute__((ext_vector_type(4))) float f32x4;
typedef __attribute__((ext_vector_type(4))) unsigned short u16x4;

__device__ inline float b2f(u16 u){ unsigned x = ((unsigned)u) << 16; float f; __builtin_memcpy(&f, &x, 4); return f; }
__device__ inline u16 f2b(float f){ __hip_bfloat16 h = __float2bfloat16(f); u16 u; __builtin_memcpy(&u, &h, 2); return u; }

// async global->LDS, 16B per lane; LDS dest = wave-uniform base + lane*16 (linear)
__device__ inline void glds16(const u16* g, u16* l) {
    __builtin_amdgcn_global_load_lds(
        (const __attribute__((address_space(1))) void*)g,
        (__attribute__((address_space(3))) void*)l, 16, 0, 0);
}

// ---------------- transpose + cast: src [K][N] f32 -> dst [N][K] bf16 ----------------
__global__ __launch_bounds__(256) void transpose_cast(const float* __restrict__ src,
                                                      u16* __restrict__ dst, int K, int N) {
    __shared__ float t[32][33];
    int nb = blockIdx.x * 32, kb = blockIdx.y * 32;
    int tx = threadIdx.x & 31, ty = threadIdx.x >> 5;
    for (int i = 0; i < 4; i++) {
        int r = ty + i * 8;
        t[r][tx] = src[(size_t)(kb + r) * N + nb + tx];
    }
    __syncthreads();
    for (int i = 0; i < 4; i++) {
        int r = ty + i * 8;
        dst[(size_t)(nb + r) * K + kb + tx] = f2b(t[tx][r]);
    }
}

// ---------------- LayerNorm row (D=1024) f32 -> bf16 ----------------
__global__ __launch_bounds__(256) void ln_bf16(const float* __restrict__ x,
                                               const float* __restrict__ w,
                                               const float* __restrict__ b,
                                               u16* __restrict__ out) {
    int row = blockIdx.x, t = threadIdx.x;
    float4 v = ((const float4*)(x + (size_t)row * 1024))[t];
    float s1 = v.x + v.y + v.z + v.w;
    float s2 = v.x * v.x + v.y * v.y + v.z * v.z + v.w * v.w;
    for (int o = 32; o > 0; o >>= 1) { s1 += __shfl_xor(s1, o); s2 += __shfl_xor(s2, o); }
    __shared__ float a1[4], a2[4];
    if ((t & 63) == 0) { a1[t >> 6] = s1; a2[t >> 6] = s2; }
    __syncthreads();
    s1 = a1[0] + a1[1] + a1[2] + a1[3];
    s2 = a2[0] + a2[1] + a2[2] + a2[3];
    float mu = s1 * (1.0f / 1024.0f);
    float var = s2 * (1.0f / 1024.0f) - mu * mu;
    float rs = rsqrtf(var + EPS_);
    float4 wv = ((const float4*)w)[t];
    float4 bv = ((const float4*)b)[t];
    u16x4 o;
    o[0] = f2b((v.x - mu) * rs * wv.x + bv.x);
    o[1] = f2b((v.y - mu) * rs * wv.y + bv.y);
    o[2] = f2b((v.z - mu) * rs * wv.z + bv.z);
    o[3] = f2b((v.w - mu) * rs * wv.w + bv.w);
    ((u16x4*)(out + (size_t)row * 1024))[t] = o;
}

// ======== 8-phase 256x256 MFMA GEMM, BK=32, 4-deep K-tile pipeline ========
// C[M,N] = A[M,K] @ Bt[N,K]^T. 512 threads = 8 waves (2M x 4N), wave tile 128x64.
// LDS: 4 bufs x {A,B} x [256 rows][32 k] swizzled: slot(r,s) = s ^ ((r>>1)&3).
// MODE 0: qkv scatter (+bias, q pre-scaled)   MODE 2: outb = gelu(acc+bias), ld 4096
template <int MODE>
__global__ __launch_bounds__(512) void gemm256_8ph(
    const u16* __restrict__ A, const u16* __restrict__ Bt,
    const float* __restrict__ bias, int K,
    u16* __restrict__ outb,
    u16* __restrict__ qp, u16* __restrict__ kp, u16* __restrict__ vtp) {
    __shared__ u16 LS[4][2][256 * 32];   // [buf][op][row*32 + off] = 128 KiB
    int tid = threadIdx.x;
    int w = tid >> 6, lane = tid & 63, g = lane >> 4, ln = lane & 15;
    int wr = w >> 2, wc = w & 3;
    // XCD-bijective block swizzle (nwg % 8 == 0 for our grids)
    int gx = gridDim.x;
    int nwg = gx * gridDim.y;
    int lin = blockIdx.y * gx + blockIdx.x;
    int swz = (lin & 7) * (nwg >> 3) + (lin >> 3);
    int bx = swz % gx, by = swz / gx;
    int br = by * 256, bc = bx * 256;
    // staging: lane covers row (lane>>2) within 16-row block, 16B slot (lane&3);
    // global col pre-swizzled so linear LDS dest + swizzled read = identity
    int jx = (((lane & 3) ^ ((lane >> 3) & 3)) << 3);
    const u16* Ast = A + (size_t)(br + w * 32 + (lane >> 2)) * K + jx;
    const u16* Bst = Bt + (size_t)(bc + w * 32 + (lane >> 2)) * K + jx;
    size_t r16 = (size_t)16 * K;
    const int ldsW = (w * 32) * 32;   // u16 index of wave's 32-row stage region
    f32x4 acc[8][4] = {};
    int NT = K >> 5;
    int slotr = ((g ^ ((ln >> 1) & 3)) << 3);
    // prologue: stage K-tiles 0,1,2
    for (int kt = 0; kt < 3; ++kt) {
        glds16(Ast + (size_t)kt * 32, &LS[kt][0][ldsW]);
        glds16(Ast + (size_t)kt * 32 + r16, &LS[kt][0][ldsW + 512]);
        glds16(Bst + (size_t)kt * 32, &LS[kt][1][ldsW]);
        glds16(Bst + (size_t)kt * 32 + r16, &LS[kt][1][ldsW + 512]);
    }
    asm volatile("s_waitcnt vmcnt(8)" ::: "memory");   // K-tile 0 landed
    __builtin_amdgcn_s_barrier();
    short8 aa[4], bb[4];
    for (int kt = 0; kt < NT; ++kt) {
        const u16* bufA = &LS[kt & 3][0][0];
        const u16* bufB = &LS[kt & 3][1][0];
        int s3 = kt + 3;
        // ---- phase 1: read A rows 0-63 + all B; stage A of kt+3; MFMA half 0
        #pragma unroll
        for (int m = 0; m < 4; ++m)
            aa[m] = *(const short8*)&bufA[(wr * 128 + m * 16 + ln) * 32 + slotr];
        #pragma unroll
        for (int n = 0; n < 4; ++n)
            bb[n] = *(const short8*)&bufB[(wc * 64 + n * 16 + ln) * 32 + slotr];
        if (s3 < NT) {
            u16* d = &LS[s3 & 3][0][ldsW];
            glds16(Ast + (size_t)s3 * 32, d);
            glds16(Ast + (size_t)s3 * 32 + r16, d + 512);
        }
        __builtin_amdgcn_s_barrier();
        asm volatile("s_waitcnt lgkmcnt(0)" ::: "memory");
        __builtin_amdgcn_sched_barrier(0);
        __builtin_amdgcn_s_setprio(1);
        #pragma unroll
        for (int m = 0; m < 4; ++m)
            #pragma unroll
            for (int n = 0; n < 4; ++n)
                acc[m][n] = __builtin_amdgcn_mfma_f32_16x16x32_bf16(aa[m], bb[n], acc[m][n], 0, 0, 0);
        __builtin_amdgcn_s_setprio(0);
        __builtin_amdgcn_sched_barrier(0);
        __builtin_amdgcn_s_barrier();
        // ---- phase 2: read A rows 64-127 (B reused); stage B of kt+3; vmcnt; MFMA half 1
        #pragma unroll
        for (int m = 0; m < 4; ++m)
            aa[m] = *(const short8*)&bufA[(wr * 128 + 64 + m * 16 + ln) * 32 + slotr];
        if (s3 < NT) {
            u16* d = &LS[s3 & 3][1][ldsW];
            glds16(Bst + (size_t)s3 * 32, d);
            glds16(Bst + (size_t)s3 * 32 + r16, d + 512);
        }
        // guard next K-tile's data; counted, never 0 in steady state
        if (kt + 3 < NT)      asm volatile("s_waitcnt vmcnt(8)" ::: "memory");
        else if (kt + 2 < NT) asm volatile("s_waitcnt vmcnt(4)" ::: "memory");
        else if (kt + 1 < NT) asm volatile("s_waitcnt vmcnt(0)" ::: "memory");
        __builtin_amdgcn_s_barrier();
        asm volatile("s_waitcnt lgkmcnt(0)" ::: "memory");
        __builtin_amdgcn_sched_barrier(0);
        __builtin_amdgcn_s_setprio(1);
        #pragma unroll
        for (int m = 0; m < 4; ++m)
            #pragma unroll
            for (int n = 0; n < 4; ++n)
                acc[4 + m][n] = __builtin_amdgcn_mfma_f32_16x16x32_bf16(aa[m], bb[n], acc[4 + m][n], 0, 0, 0);
        __builtin_amdgcn_s_setprio(0);
        __builtin_amdgcn_sched_barrier(0);
        __builtin_amdgcn_s_barrier();
    }
    // epilogue
    #pragma unroll
    for (int m = 0; m < 8; ++m) {
        int row0 = br + wr * 128 + m * 16 + g * 4;
        #pragma unroll
        for (int n = 0; n < 4; ++n) {
            int col = bc + wc * 64 + n * 16 + ln;
            float bv = bias[col];
            if constexpr (MODE == 0) {
                int which = col >> 10, cc = col & 1023, hh = cc >> 6, dh = cc & 63;
                int bb2 = row0 >> 11, nn0 = row0 & 2047;
                size_t bh = (size_t)(bb2 * 16 + hh);
                if (which == 0) {
                    for (int r = 0; r < 4; r++)
                        qp[((bh * 2048 + nn0 + r) << 6) + dh] = f2b((acc[m][n][r] + bv) * SC2_);
                } else if (which == 1) {
                    for (int r = 0; r < 4; r++)
                        kp[((bh * 2048 + nn0 + r) << 6) + dh] = f2b(acc[m][n][r] + bv);
                } else {
                    u16x4 o;
                    for (int r = 0; r < 4; r++) o[r] = f2b(acc[m][n][r] + bv);
                    *(u16x4*)&vtp[((bh * 64 + dh) << 11) + nn0] = o;
                }
            } else {
                for (int r = 0; r < 4; r++) {
                    float v = acc[m][n][r] + bv;
                    float gl = 0.5f * v * (1.0f + erff(v * 0.7071067811865476f));
                    outb[(size_t)(row0 + r) * 4096 + col] = f2b(gl);
                }
            }
        }
    }
}

// ---------------- bf16 GEMM (R3 structure): C[M,N] = A[M,K] @ Bt[N,K]^T ----------------
// MODE 1: outf = res + acc + bias    MODE 3: outf += acc + bias
template <int MODE, int BN>
__global__ __launch_bounds__(256) void gemm_bf16(
    const u16* __restrict__ A, const u16* __restrict__ Bt,
    const float* __restrict__ bias, int M, int N, int K,
    const float* __restrict__ res, float* __restrict__ outf) {
    constexpr int NN = BN / 32;
    __shared__ u16 As[128 * 64];
    __shared__ u16 Bs[BN * 64];
    int br = blockIdx.y * 128, bc = blockIdx.x * BN;
    int tid = threadIdx.x;
    int w = tid >> 6, lane = tid & 63, g = lane >> 4, ln = lane & 15;
    int wr = (w >> 1) * 64, wc = (w & 1) * (BN / 2);
    f32x4 acc[4][NN] = {};
    int sgcol = (((lane & 7) ^ (lane >> 3)) << 3);
    int arow = w * 32 + (lane >> 3);
    int brow = w * (BN / 4) + (lane >> 3);
    const u16* Ap = A + (size_t)(br + arow) * K + sgcol;
    const u16* Bp = Bt + (size_t)(bc + brow) * K + sgcol;
    u16* lA = &As[(w * 32) * 64];
    u16* lB = &Bs[(w * (BN / 4)) * 64];
    size_t rstep = (size_t)8 * K;
    for (int kt = 0; kt < K; kt += 64) {
        __syncthreads();
        #pragma unroll
        for (int i = 0; i < 4; i++) glds16(Ap + kt + i * rstep, lA + i * 512);
        #pragma unroll
        for (int i = 0; i < BN / 32; i++) glds16(Bp + kt + i * rstep, lB + i * 512);
        __syncthreads();
        #pragma unroll
        for (int kk = 0; kk < 2; kk++) {
            int so = (((kk << 2) + g) ^ (ln & 7)) << 3;
            short8 af[4], bfr[NN];
            #pragma unroll
            for (int m = 0; m < 4; m++)  af[m]  = *(const short8*)&As[(wr + m * 16 + ln) * 64 + so];
            #pragma unroll
            for (int n = 0; n < NN; n++) bfr[n] = *(const short8*)&Bs[(wc + n * 16 + ln) * 64 + so];
            #pragma unroll
            for (int m = 0; m < 4; m++)
                #pragma unroll
                for (int n = 0; n < NN; n++)
                    acc[m][n] = __builtin_amdgcn_mfma_f32_16x16x32_bf16(af[m], bfr[n], acc[m][n], 0, 0, 0);
        }
    }
    #pragma unroll
    for (int m = 0; m < 4; m++) {
        int row0 = br + wr + m * 16 + g * 4;
        #pragma unroll
        for (int n = 0; n < NN; n++) {
            int col = bc + wc + n * 16 + ln;
            float bv = bias[col];
            if constexpr (MODE == 1) {
                for (int r = 0; r < 4; r++) {
                    size_t idx = (size_t)(row0 + r) * 1024 + col;
                    outf[idx] = res[idx] + acc[m][n][r] + bv;
                }
            } else {
                for (int r = 0; r < 4; r++) {
                    size_t idx = (size_t)(row0 + r) * 1024 + col;
                    outf[idx] = outf[idx] + acc[m][n][r] + bv;
                }
            }
        }
    }
}

// ---------------- flash attention: swapped QK^T, dbuf LDS, 1 barrier/tile ----------------
// grid (32 q-tiles, 32 bh), 4 waves/wg; q pre-scaled by SCALE*LOG2E; dist raw f32.
__global__ __launch_bounds__(256) void attn_fwd(
    const u16* __restrict__ qg, const u16* __restrict__ kg, const u16* __restrict__ vtg,
    const float* __restrict__ dist, const float* __restrict__ gamma, u16* __restrict__ ao) {
    __shared__ u16 Ks[2][64 * 64];
    __shared__ u16 Vs[2][64 * 64];
    __shared__ u16 Ps[4][16 * 64];
    int qt = blockIdx.x, bh = blockIdx.y;
    int b = bh >> 4, h = bh & 15;
    int tid = threadIdx.x, w = tid >> 6, lane = tid & 63, g = lane >> 4, ln = lane & 15;
    float gam2 = gamma[bh] * LOG2E_;
    int qglob = qt * 64 + w * 16 + ln;
    const u16* qrow = qg + ((size_t)bh * 2048 + qglob) * 64;
    short8 qf0 = *(const short8*)(qrow + g * 8);
    short8 qf1 = *(const short8*)(qrow + 32 + g * 8);
    const float* dbase = dist + (size_t)qglob * 2048 + g * 4;
    float m2 = -3.0e38f;
    f32x4 acco[4] = {};
    f32x4 accl = {};            // ones-MFMA softmax denominator
    short8 ones;
    #pragma unroll
    for (int i = 0; i < 8; ++i) ones[i] = (short)0x3F80;   // bf16 1.0
    int srow = tid >> 2, sc = (tid & 3) * 2;
    int ss0 = ((sc ^ (srow & 7)) << 3), ss1 = (((sc + 1) ^ (srow & 7)) << 3);
    const u16* kgp = kg + ((size_t)bh * 2048 + srow) * 64 + sc * 8;
    const u16* vgp = vtg + ((size_t)bh * 64 + srow) * 2048 + sc * 8;
    {
        short8 a0 = *(const short8*)(kgp);
        short8 a1 = *(const short8*)(kgp + 8);
        short8 c0 = *(const short8*)(vgp);
        short8 c1 = *(const short8*)(vgp + 8);
        *(short8*)&Ks[0][srow * 64 + ss0] = a0;
        *(short8*)&Ks[0][srow * 64 + ss1] = a1;
        *(short8*)&Vs[0][srow * 64 + ss0] = c0;
        *(short8*)&Vs[0][srow * 64 + ss1] = c1;
    }
    float4 dcv[4];
    #pragma unroll
    for (int nb = 0; nb < 4; nb++) dcv[nb] = *(const float4*)(dbase + nb * 16);
    __syncthreads();
    int cur = 0;
    int so0 = (g ^ (ln & 7)) << 3, so1 = ((4 + g) ^ (ln & 7)) << 3;
    for (int kt = 0; kt < 32; kt++) {
        short8 kr0, kr1, vr0, vr1;
        float4 dnx[4];
        if (kt < 31) {
            kr0 = *(const short8*)(kgp + (kt + 1) * 4096);
            kr1 = *(const short8*)(kgp + (kt + 1) * 4096 + 8);
            vr0 = *(const short8*)(vgp + (kt + 1) * 64);
            vr1 = *(const short8*)(vgp + (kt + 1) * 64 + 8);
            #pragma unroll
            for (int nb = 0; nb < 4; nb++)
                dnx[nb] = *(const float4*)(dbase + (kt + 1) * 64 + nb * 16);
        }
        f32x4 sa[4] = {};
        __builtin_amdgcn_s_setprio(1);
        #pragma unroll
        for (int nb = 0; nb < 4; nb++) {
            short8 kf0 = *(const short8*)&Ks[cur][(nb * 16 + ln) * 64 + so0];
            short8 kf1 = *(const short8*)&Ks[cur][(nb * 16 + ln) * 64 + so1];
            sa[nb] = __builtin_amdgcn_mfma_f32_16x16x32_bf16(kf0, qf0, sa[nb], 0, 0, 0);
            sa[nb] = __builtin_amdgcn_mfma_f32_16x16x32_bf16(kf1, qf1, sa[nb], 0, 0, 0);
        }
        __builtin_amdgcn_s_setprio(0);
        float sv[4][4], pm = -3.0e38f;
        #pragma unroll
        for (int nb = 0; nb < 4; nb++) {
            float4 dv = dcv[nb];
            sv[nb][0] = sa[nb][0] - gam2 * dv.x;
            sv[nb][1] = sa[nb][1] - gam2 * dv.y;
            sv[nb][2] = sa[nb][2] - gam2 * dv.z;
            sv[nb][3] = sa[nb][3] - gam2 * dv.w;
            #pragma unroll
            for (int r = 0; r < 4; r++) pm = fmaxf(pm, sv[nb][r]);
        }
        pm = fmaxf(pm, __shfl_xor(pm, 16));
        pm = fmaxf(pm, __shfl_xor(pm, 32));
        if (!__all(pm - m2 <= 8.0f)) {
            float nm = fmaxf(m2, pm);
            float al = __builtin_exp2f(m2 - nm);
            m2 = nm;
            accl *= al;
            #pragma unroll
            for (int db = 0; db < 4; db++) acco[db] *= al;
        }
        #pragma unroll
        for (int nb = 0; nb < 4; nb++) {
            u16x4 pw;
            #pragma unroll
            for (int r = 0; r < 4; r++) pw[r] = f2b(__builtin_exp2f(sv[nb][r] - m2));
            int off = nb * 16 + g * 4;
            *(u16x4*)&Ps[w][ln * 64 + (((off >> 3) ^ (ln & 7)) << 3) + (off & 7)] = pw;
        }
        short8 pf0 = *(const short8*)&Ps[w][ln * 64 + so0];
        short8 pf1 = *(const short8*)&Ps[w][ln * 64 + so1];
        __builtin_amdgcn_s_setprio(1);
        #pragma unroll
        for (int db = 0; db < 4; db++) {
            short8 vf0 = *(const short8*)&Vs[cur][(db * 16 + ln) * 64 + so0];
            short8 vf1 = *(const short8*)&Vs[cur][(db * 16 + ln) * 64 + so1];
            acco[db] = __builtin_amdgcn_mfma_f32_16x16x32_bf16(vf0, pf0, acco[db], 0, 0, 0);
            acco[db] = __builtin_amdgcn_mfma_f32_16x16x32_bf16(vf1, pf1, acco[db], 0, 0, 0);
        }
        accl = __builtin_amdgcn_mfma_f32_16x16x32_bf16(ones, pf0, accl, 0, 0, 0);
        accl = __builtin_amdgcn_mfma_f32_16x16x32_bf16(ones, pf1, accl, 0, 0, 0);
        __builtin_amdgcn_s_setprio(0);
        if (kt < 31) {
            int nx = cur ^ 1;
            *(short8*)&Ks[nx][srow * 64 + ss0] = kr0;
            *(short8*)&Ks[nx][srow * 64 + ss1] = kr1;
            *(short8*)&Vs[nx][srow * 64 + ss0] = vr0;
            *(short8*)&Vs[nx][srow * 64 + ss1] = vr1;
            #pragma unroll
            for (int nb = 0; nb < 4; nb++) dcv[nb] = dnx[nb];
            __syncthreads();
            cur = nx;
        }
    }
    float inv = 1.0f / accl[0];
    u16* aop = ao + (size_t)(b * 2048 + qglob) * 1024 + h * 64 + g * 4;
    #pragma unroll
    for (int db = 0; db < 4; db++) {
        u16x4 o;
        #pragma unroll
        for (int r = 0; r < 4; r++) o[r] = f2b(acco[db][r] * inv);
        *(u16x4*)(aop + db * 16) = o;
    }
}

extern "C" void kernel_launch(void* const* d_in, const int* in_sizes, int n_in,
                              void* d_out, int out_size, void* d_ws, size_t ws_size,
                              hipStream_t stream) {
    const float* x     = (const float*)d_in[0];
    const float* gamma = (const float*)d_in[1];
    const float* dist  = (const float*)d_in[2];
    const float* ln1w  = (const float*)d_in[3];
    const float* ln1b  = (const float*)d_in[4];
    const float* qkvw  = (const float*)d_in[5];
    const float* qkvb  = (const float*)d_in[6];
    const float* projw = (const float*)d_in[7];
    const float* projb = (const float*)d_in[8];
    const float* ln2w  = (const float*)d_in[9];
    const float* ln2b  = (const float*)d_in[10];
    const float* w1    = (const float*)d_in[11];
    const float* b1    = (const float*)d_in[12];
    const float* w2    = (const float*)d_in[13];
    const float* b2    = (const float*)d_in[14];
    float* out = (float*)d_out;
    char* ws = (char*)d_ws;
    u16* wqkvT  = (u16*)(ws + 0);
    u16* wprojT = (u16*)(ws + 6291456);
    u16* w1T    = (u16*)(ws + 8388608);
    u16* w2T    = (u16*)(ws + 16777216);
    u16* hb     = (u16*)(ws + 33554432);
    u16* qb     = (u16*)(ws + 41943040);
    u16* kb     = (u16*)(ws + 50331648);
    u16* vtb    = (u16*)(ws + 58720256);
    u16* aob    = (u16*)(ws + 67108864);
    u16* gb     = hb;    // mlp1 output reuses h..vT region (dead by then)
    u16* h2b    = aob;   // ln2 output reuses ao slot (dead after proj)

    dim3 blk(256);
    transpose_cast<<<dim3(3072 / 32, 1024 / 32), blk, 0, stream>>>(qkvw, wqkvT, 1024, 3072);
    transpose_cast<<<dim3(1024 / 32, 1024 / 32), blk, 0, stream>>>(projw, wprojT, 1024, 1024);
    transpose_cast<<<dim3(4096 / 32, 1024 / 32), blk, 0, stream>>>(w1, w1T, 1024, 4096);
    transpose_cast<<<dim3(1024 / 32, 4096 / 32), blk, 0, stream>>>(w2, w2T, 4096, 1024);
    ln_bf16<<<4096, blk, 0, stream>>>(x, ln1w, ln1b, hb);
    gemm256_8ph<0><<<dim3(12, 16), dim3(512), 0, stream>>>(hb, wqkvT, qkvb, 1024,
                                                           nullptr, qb, kb, vtb);
    attn_fwd<<<dim3(32, 32), blk, 0, stream>>>(qb, kb, vtb, dist, gamma, aob);
    gemm_bf16<1, 64><<<dim3(16, 32), blk, 0, stream>>>(aob, wprojT, projb, 4096, 1024, 1024,
                                                       x, out);
    ln_bf16<<<4096, blk, 0, stream>>>(out, ln2w, ln2b, h2b);
    gemm256_8ph<2><<<dim3(16, 16), dim3(512), 0, stream>>>(h2b, w1T, b1, 1024,
                                                           gb, nullptr, nullptr, nullptr);
    gemm_bf16<3, 64><<<dim3(16, 32), blk, 0, stream>>>(gb, w2T, b2, 4096, 1024, 4096,
                                                       nullptr, out);
}